// Round 1
// baseline (205.550 us; speedup 1.0000x reference)
//
#include <hip/hip_runtime.h>

using bf16x8 = __attribute__((ext_vector_type(8))) short;
using f32x4  = __attribute__((ext_vector_type(4))) float;

static __device__ __forceinline__ short f2bf(float f) {
  union { float f; unsigned u; } x; x.f = f;
  unsigned r = x.u + 0x7fffu + ((x.u >> 16) & 1u);
  return (short)(r >> 16);
}

// ---------------- mask handling ----------------
// Detect whether the bool mask arrived as 1-byte or 4-byte elements.
// Random 0/1 bytes read as u32 exceed 1 with prob 1-(1/8) per word.
__global__ void k_detect_mask(const unsigned* __restrict__ m, int* __restrict__ flag) {
  if (threadIdx.x == 0) {
    int f = 0;
    for (int i = 0; i < 256; ++i) { if (m[i] > 1u) { f = 1; break; } }
    *flag = f;  // 1 = uint8 storage, 0 = int32 storage
  }
}

__global__ void k_convert_mask(const void* __restrict__ src, unsigned char* __restrict__ dst,
                               const int* __restrict__ flag, int n) {
  const int f = *flag;
  const unsigned char* s8 = (const unsigned char*)src;
  const int* s32 = (const int*)src;
  for (int i = blockIdx.x * blockDim.x + threadIdx.x; i < n; i += gridDim.x * blockDim.x)
    dst[i] = f ? (unsigned char)(s8[i] != 0) : (unsigned char)(s32[i] != 0);
}

// ---------------- f32 -> bf16 ----------------
__global__ void k_cvt_bf16(const float* __restrict__ in, short* __restrict__ out, int n4) {
  for (int i = blockIdx.x * blockDim.x + threadIdx.x; i < n4; i += gridDim.x * blockDim.x) {
    float4 v = reinterpret_cast<const float4*>(in)[i];
    short4 o;
    o.x = f2bf(v.x); o.y = f2bf(v.y); o.z = f2bf(v.z); o.w = f2bf(v.w);
    reinterpret_cast<short4*>(out)[i] = o;
  }
}

// transpose 1024x1024 f32 W[k][n] -> bf16 Wt[n][k]
__global__ void k_transpose_cvt(const float* __restrict__ in, short* __restrict__ out) {
  __shared__ float tile[32][33];
  int x = blockIdx.x * 32 + threadIdx.x;       // n
  int y0 = blockIdx.y * 32;                    // k
  for (int j = 0; j < 32; j += 8)
    tile[threadIdx.y + j][threadIdx.x] = in[(size_t)(y0 + threadIdx.y + j) * 1024 + x];
  __syncthreads();
  int xo = blockIdx.y * 32 + threadIdx.x;      // k
  int yo = blockIdx.x * 32;                    // n
  for (int j = 0; j < 32; j += 8)
    out[(size_t)(yo + threadIdx.y + j) * 1024 + xo] = f2bf(tile[threadIdx.x][threadIdx.y + j]);
}

// ---------------- bf16 MFMA GEMM: C = A @ Bt^T + bias ----------------
// A: [M][K] bf16 row-major, Bt: [N][K] bf16 row-major (pre-transposed W)
template<int OUT_BF16>
__launch_bounds__(256)
__global__ void k_gemm(const short* __restrict__ A, const short* __restrict__ Bt,
                       const float* __restrict__ bias, void* __restrict__ C,
                       int M, int N, int K) {
  __shared__ short Al[128][40];  // +8 pad: 80B row stride -> 2-way bank alias (free)
  __shared__ short Bl[128][40];
  const int tid  = threadIdx.x;
  const int lane = tid & 63, wid = tid >> 6;
  const int lr   = lane & 15, koff = (lane >> 4) * 8;
  const int wm   = wid >> 1, wn = wid & 1;
  const int m0   = blockIdx.y * 128, n0 = blockIdx.x * 128;

  f32x4 acc[4][4];
  for (int i = 0; i < 4; ++i)
    for (int j = 0; j < 4; ++j) acc[i][j] = (f32x4){0.f, 0.f, 0.f, 0.f};

  for (int kt = 0; kt < K; kt += 32) {
    for (int c = 0; c < 2; ++c) {
      int ch = c * 256 + tid;        // 0..511 chunks of 16B
      int row = ch >> 2;             // 0..127
      int off = (ch & 3) * 8;        // 0,8,16,24
      *reinterpret_cast<bf16x8*>(&Al[row][off]) =
          *reinterpret_cast<const bf16x8*>(&A[(size_t)(m0 + row) * K + kt + off]);
      *reinterpret_cast<bf16x8*>(&Bl[row][off]) =
          *reinterpret_cast<const bf16x8*>(&Bt[(size_t)(n0 + row) * K + kt + off]);
    }
    __syncthreads();
    bf16x8 af[4], bfr[4];
    for (int i = 0; i < 4; ++i)
      af[i]  = *reinterpret_cast<const bf16x8*>(&Al[wm * 64 + i * 16 + lr][koff]);
    for (int j = 0; j < 4; ++j)
      bfr[j] = *reinterpret_cast<const bf16x8*>(&Bl[wn * 64 + j * 16 + lr][koff]);
    for (int i = 0; i < 4; ++i)
      for (int j = 0; j < 4; ++j)
        acc[i][j] = __builtin_amdgcn_mfma_f32_16x16x32_bf16(af[i], bfr[j], acc[i][j], 0, 0, 0);
    __syncthreads();
  }

  for (int i = 0; i < 4; ++i) {
    int row = m0 + wm * 64 + i * 16 + (lane >> 4) * 4;
    for (int j = 0; j < 4; ++j) {
      int col = n0 + wn * 64 + j * 16 + lr;
      float bv = bias[col];
      for (int r = 0; r < 4; ++r) {
        float v = acc[i][j][r] + bv;
        if (OUT_BF16) ((short*)C)[(size_t)(row + r) * N + col] = f2bf(v);
        else          ((float*)C)[(size_t)(row + r) * N + col] = v;
      }
    }
  }
}

// ---------------- fused masked attention (V = projected Q) ----------------
// block = (b, h, 64 q-rows); 4 waves x 16 q-rows; flash over 16 tiles of 64 keys
__launch_bounds__(256)
__global__ void k_attention(const short* __restrict__ Qp, const short* __restrict__ Kp,
                            const unsigned char* __restrict__ mask, short* __restrict__ O) {
  __shared__ short Kl[64][72];      // K-tile [key][d], +8 pad
  __shared__ short Vt[64][72];      // V-tile transposed [d][key]
  __shared__ short Pl[4][16][72];   // per-wave P [qrow][key]
  const int tid  = threadIdx.x;
  const int lane = tid & 63, wid = tid >> 6;
  const int lr   = lane & 15, koff = (lane >> 4) * 8;
  const int bid  = blockIdx.x;
  const int qt = bid & 15, h = (bid >> 4) & 15, b = bid >> 8;
  const int qr0 = qt * 64 + wid * 16;                 // q row within S
  const int qrow_base = qr0 + (lane >> 4) * 4;        // C-frag rows

  // Q fragments hoisted (A-operand of QK^T), 64-d split into 2 mfma K-blocks
  bf16x8 aq[2];
  for (int db = 0; db < 2; ++db)
    aq[db] = *reinterpret_cast<const bf16x8*>(
        &Qp[(size_t)(b * 1024 + qr0 + lr) * 1024 + h * 64 + db * 32 + koff]);

  f32x4 o[4];
  for (int d = 0; d < 4; ++d) o[d] = (f32x4){0.f, 0.f, 0.f, 0.f};
  float m_run[4], l_run[4];
  for (int r = 0; r < 4; ++r) { m_run[r] = -INFINITY; l_run[r] = 0.f; }

  for (int kt = 0; kt < 16; ++kt) {
    // stage K tile and transposed V tile (V = projected Q rows)
    for (int c = 0; c < 2; ++c) {
      int ch = c * 256 + tid;         // 512 chunks of 16B
      int row = ch >> 3;              // key row 0..63
      int off = (ch & 7) * 8;         // d offset 0..56
      size_t gsrc = (size_t)(b * 1024 + kt * 64 + row) * 1024 + h * 64 + off;
      *reinterpret_cast<bf16x8*>(&Kl[row][off]) =
          *reinterpret_cast<const bf16x8*>(&Kp[gsrc]);
      bf16x8 v = *reinterpret_cast<const bf16x8*>(&Qp[gsrc]);
      for (int j = 0; j < 8; ++j) Vt[off + j][row] = v[j];
    }
    __syncthreads();

    // QK^T: scores [16 q][64 k] as 4 C-frags
    f32x4 s[4];
    for (int kc = 0; kc < 4; ++kc) {
      f32x4 a = (f32x4){0.f, 0.f, 0.f, 0.f};
      for (int db = 0; db < 2; ++db) {
        bf16x8 kb = *reinterpret_cast<const bf16x8*>(&Kl[kc * 16 + lr][db * 32 + koff]);
        a = __builtin_amdgcn_mfma_f32_16x16x32_bf16(aq[db], kb, a, 0, 0, 0);
      }
      s[kc] = a;
    }

    // scale by 1/sqrt(64), apply mask (exact -1e9 like reference)
    for (int r = 0; r < 4; ++r) {
      const unsigned char* mrow =
          &mask[(size_t)(b * 1024 + qrow_base + r) * 1024 + kt * 64];
      for (int kc = 0; kc < 4; ++kc) {
        float v = s[kc][r] * 0.125f;
        if (mrow[kc * 16 + lr]) v = -1e9f;
        s[kc][r] = v;
      }
    }

    // online softmax (f32); rows live across 16 lanes (lr), 4 regs each
    float p[4][4], mn[4], psum[4];
    for (int r = 0; r < 4; ++r) {
      float v = fmaxf(fmaxf(s[0][r], s[1][r]), fmaxf(s[2][r], s[3][r]));
      v = fmaxf(v, __shfl_xor(v, 1));
      v = fmaxf(v, __shfl_xor(v, 2));
      v = fmaxf(v, __shfl_xor(v, 4));
      v = fmaxf(v, __shfl_xor(v, 8));
      mn[r] = fmaxf(m_run[r], v);
      psum[r] = 0.f;
    }
    for (int kc = 0; kc < 4; ++kc)
      for (int r = 0; r < 4; ++r) {
        float pv = __expf(s[kc][r] - mn[r]);
        p[kc][r] = pv;
        psum[r] += pv;
      }
    for (int r = 0; r < 4; ++r) {
      float v = psum[r];
      v += __shfl_xor(v, 1);
      v += __shfl_xor(v, 2);
      v += __shfl_xor(v, 4);
      v += __shfl_xor(v, 8);
      float sc = __expf(m_run[r] - mn[r]);   // exp(-inf)=0 on first tile
      l_run[r] = l_run[r] * sc + v;
      m_run[r] = mn[r];
      for (int d = 0; d < 4; ++d) o[d][r] *= sc;
    }

    // P (C-layout) -> LDS -> A-layout for PV
    for (int kc = 0; kc < 4; ++kc)
      for (int r = 0; r < 4; ++r)
        Pl[wid][(lane >> 4) * 4 + r][kc * 16 + lr] = f2bf(p[kc][r]);

    for (int d = 0; d < 4; ++d)
      for (int kb = 0; kb < 2; ++kb) {
        bf16x8 pa = *reinterpret_cast<const bf16x8*>(&Pl[wid][lr][kb * 32 + koff]);
        bf16x8 vb = *reinterpret_cast<const bf16x8*>(&Vt[d * 16 + lr][kb * 32 + koff]);
        o[d] = __builtin_amdgcn_mfma_f32_16x16x32_bf16(pa, vb, o[d], 0, 0, 0);
      }
    __syncthreads();
  }

  // epilogue: normalize, redundant row-zeroing (~mask[b,q,0]), store bf16
  for (int r = 0; r < 4; ++r) {
    float keep = mask[(size_t)(b * 1024 + qrow_base + r) * 1024] ? 0.f : 1.f;
    float inv = (l_run[r] > 0.f) ? keep / l_run[r] : 0.f;
    for (int d = 0; d < 4; ++d) {
      float v = o[d][r] * inv;
      O[(size_t)(b * 1024 + qrow_base + r) * 1024 + h * 64 + d * 16 + lr] = f2bf(v);
    }
  }
}

extern "C" void kernel_launch(void* const* d_in, const int* in_sizes, int n_in,
                              void* d_out, int out_size, void* d_ws, size_t ws_size,
                              hipStream_t stream) {
  const float* query  = (const float*)d_in[0];
  const float* key_in = (const float*)d_in[1];
  const void*  mask_raw = d_in[2];
  const float* Wq = (const float*)d_in[3];
  const float* bq = (const float*)d_in[4];
  const float* Wk = (const float*)d_in[5];
  const float* bk = (const float*)d_in[6];
  const float* Wp = (const float*)d_in[7];
  const float* bp = (const float*)d_in[8];

  char* ws = (char*)d_ws;
  size_t off = 0;
  auto alloc = [&](size_t bytes) {
    char* p = ws + off;
    off = (off + bytes + 255) & ~(size_t)255;
    return p;
  };
  unsigned char* mask_u8 = (unsigned char*)alloc(4ull << 20);   // [4][1024][1024]
  int*   flag  = (int*)alloc(256);
  short* Qbf   = (short*)alloc(8ull << 20);   // query bf16 [4096][1024]
  short* Kbf   = (short*)alloc(8ull << 20);   // key bf16; reused as AttnO later
  short* Wt    = (short*)alloc(2ull << 20);   // transposed weight (reused x3)
  short* Qproj = (short*)alloc(8ull << 20);
  short* Kproj = (short*)alloc(8ull << 20);
  short* AttnO = Kbf;  // Kbf dead after K projection

  const int nmask = 4 * 1024 * 1024;
  k_detect_mask<<<1, 64, 0, stream>>>((const unsigned*)mask_raw, flag);
  k_convert_mask<<<2048, 256, 0, stream>>>(mask_raw, mask_u8, flag, nmask);
  k_cvt_bf16<<<1024, 256, 0, stream>>>(query, Qbf, (4 * 1024 * 1024) / 4);
  k_cvt_bf16<<<1024, 256, 0, stream>>>(key_in, Kbf, (4 * 1024 * 1024) / 4);

  dim3 tb(32, 8), tg(32, 32);
  dim3 gb(8, 32);  // N/128, M/128

  k_transpose_cvt<<<tg, tb, 0, stream>>>(Wq, Wt);
  k_gemm<1><<<gb, 256, 0, stream>>>(Qbf, Wt, bq, Qproj, 4096, 1024, 1024);
  k_transpose_cvt<<<tg, tb, 0, stream>>>(Wk, Wt);
  k_gemm<1><<<gb, 256, 0, stream>>>(Kbf, Wt, bk, Kproj, 4096, 1024, 1024);

  k_attention<<<1024, 256, 0, stream>>>(Qproj, Kproj, mask_u8, AttnO);

  k_transpose_cvt<<<tg, tb, 0, stream>>>(Wp, Wt);
  k_gemm<0><<<gb, 256, 0, stream>>>(AttnO, Wt, bp, (float*)d_out, 4096, 1024, 1024);
}

// Round 2
// 133.147 us; speedup vs baseline: 1.5438x; 1.5438x over previous
//
#include <hip/hip_runtime.h>

using bf16x8 = __attribute__((ext_vector_type(8))) short;
using f32x4  = __attribute__((ext_vector_type(4))) float;

static __device__ __forceinline__ short f2bf(float f) {
  union { float f; unsigned u; } x; x.f = f;
  unsigned r = x.u + 0x7fffu + ((x.u >> 16) & 1u);
  return (short)(r >> 16);
}
static __device__ __forceinline__ unsigned pack_bf2(float lo, float hi) {
  return (unsigned)(unsigned short)f2bf(lo) | ((unsigned)(unsigned short)f2bf(hi) << 16);
}
static __device__ __forceinline__ void gll16(const void* g, void* l) {
  __builtin_amdgcn_global_load_lds((__attribute__((address_space(1))) const void*)g,
                                   (__attribute__((address_space(3))) void*)l, 16, 0, 0);
}

// ---------------- mask dtype detect (u8 vs i32) ----------------
__global__ void k_detect_mask(const unsigned* __restrict__ m, int* __restrict__ flag) {
  unsigned v = m[threadIdx.x];                // 64 threads, first 256 bytes
  unsigned long long b = __ballot(v > 1u);    // random 0/1 bytes as u32 are >1 w.h.p.
  if (threadIdx.x == 0) *flag = (b != 0ull);  // 1 = uint8 storage, 0 = int32 storage
}

// ---------------- mask -> bit-packed u64 per (row, 64-key tile) ----------------
__global__ void k_pack_mask(const void* __restrict__ src, const int* __restrict__ flag,
                            unsigned long long* __restrict__ out) {
  int e = blockIdx.x * 256 + threadIdx.x;     // flat element index
  int f = *flag;
  int v = f ? (int)((const unsigned char*)src)[e] : ((const int*)src)[e];
  unsigned long long b = __ballot(v != 0);    // lane i -> bit i, elements wave-contiguous
  if ((threadIdx.x & 63) == 0) out[e >> 6] = b;
}

// ---------------- f32 -> bf16 ----------------
__global__ void k_cvt_bf16(const float* __restrict__ in, short* __restrict__ out, int n4) {
  for (int i = blockIdx.x * blockDim.x + threadIdx.x; i < n4; i += gridDim.x * blockDim.x) {
    float4 v = reinterpret_cast<const float4*>(in)[i];
    short4 o;
    o.x = f2bf(v.x); o.y = f2bf(v.y); o.z = f2bf(v.z); o.w = f2bf(v.w);
    reinterpret_cast<short4*>(out)[i] = o;
  }
}

// transpose 1024x1024 f32 W[k][n] -> bf16 Wt[n][k]
__global__ void k_transpose_cvt(const float* __restrict__ in, short* __restrict__ out) {
  __shared__ float tile[32][33];
  int x = blockIdx.x * 32 + threadIdx.x;
  int y0 = blockIdx.y * 32;
  for (int j = 0; j < 32; j += 8)
    tile[threadIdx.y + j][threadIdx.x] = in[(size_t)(y0 + threadIdx.y + j) * 1024 + x];
  __syncthreads();
  int xo = blockIdx.y * 32 + threadIdx.x;
  int yo = blockIdx.x * 32;
  for (int j = 0; j < 32; j += 8)
    out[(size_t)(yo + threadIdx.y + j) * 1024 + xo] = f2bf(tile[threadIdx.x][threadIdx.y + j]);
}

// transpose bf16 Qp[b, s, h*64+d] -> Vtg[(b*16+h)*64+d][s]  (per-head V^T)
__global__ void k_vt_transpose(const short* __restrict__ Qp, short* __restrict__ Vtg) {
  __shared__ short T[64 * 64];                  // linear, chunk^row&7 swizzle
  const int st = blockIdx.x, h = blockIdx.y, b = blockIdx.z;
  const int tid = threadIdx.x;
#pragma unroll
  for (int c = 0; c < 2; ++c) {
    int ch = c * 256 + tid;                     // 512 chunks of 16B
    int row = ch >> 3, cn = ch & 7;             // row = s-local, cn = d-chunk
    bf16x8 v = *reinterpret_cast<const bf16x8*>(
        &Qp[(size_t)(b * 1024 + st * 64 + row) * 1024 + h * 64 + cn * 8]);
    *reinterpret_cast<bf16x8*>(&T[row * 64 + ((cn ^ (row & 7)) * 8)]) = v;
  }
  __syncthreads();
#pragma unroll
  for (int c = 0; c < 2; ++c) {
    int ch = c * 256 + tid;
    int d = ch >> 3, sc = ch & 7;
    bf16x8 v;
#pragma unroll
    for (int j = 0; j < 8; ++j) {
      int s_loc = sc * 8 + j;
      v[j] = T[s_loc * 64 + (((d >> 3) ^ j) * 8) + (d & 7)];
    }
    *reinterpret_cast<bf16x8*>(
        &Vtg[(size_t)((b * 16 + h) * 64 + d) * 1024 + st * 64 + sc * 8]) = v;
  }
}

// ---------------- bf16 MFMA GEMM: C = A @ Bt^T + bias ----------------
// 128x64 tile, BK=64, global_load_lds (source-swizzled, linear LDS), 2-phase dbuf
template<int OUT_BF16>
__launch_bounds__(256)
__global__ void k_gemm(const short* __restrict__ A, const short* __restrict__ Bt,
                       const float* __restrict__ bias, void* __restrict__ C,
                       int M, int N, int K) {
  __shared__ short Al[2][128 * 64];
  __shared__ short Bl[2][64 * 64];
  const int tid  = threadIdx.x;
  const int lane = tid & 63, wid = tid >> 6;
  const int g = lane >> 4, lr = lane & 15;
  const int wm = wid >> 1, wn = wid & 1;
  const int m0 = blockIdx.y * 128, n0 = blockIdx.x * 64;
  const int srow = lane >> 3;
  const int sch  = ((lane & 7) ^ srow) * 8;     // source chunk swizzle (row&7 == srow)

  f32x4 acc[4][2];
#pragma unroll
  for (int i = 0; i < 4; ++i)
#pragma unroll
    for (int j = 0; j < 2; ++j) acc[i][j] = (f32x4){0.f, 0.f, 0.f, 0.f};

  const int NT = K >> 6;
  auto stage = [&](int buf, int kt) {
#pragma unroll
    for (int s = 0; s < 4; ++s)
      gll16(&A[(size_t)(m0 + s * 32 + wid * 8 + srow) * K + kt + sch],
            &Al[buf][(s * 32 + wid * 8) * 64]);
#pragma unroll
    for (int s = 0; s < 2; ++s)
      gll16(&Bt[(size_t)(n0 + s * 32 + wid * 8 + srow) * K + kt + sch],
            &Bl[buf][(s * 32 + wid * 8) * 64]);
  };

  stage(0, 0);
  for (int t = 0; t < NT; ++t) {
    const int cur = t & 1;
    if (t + 1 < NT) {
      stage(cur ^ 1, (t + 1) * 64);
      asm volatile("s_waitcnt vmcnt(6)" ::: "memory");   // cur buffer drained, prefetch in flight
    } else {
      asm volatile("s_waitcnt vmcnt(0)" ::: "memory");
    }
    __builtin_amdgcn_s_barrier();
    asm volatile("" ::: "memory");
#pragma unroll
    for (int kb = 0; kb < 2; ++kb) {
      const int cs = ((kb * 4 + g) ^ (lr & 7)) * 8;      // swizzled read chunk
      bf16x8 af[4], bfr[2];
#pragma unroll
      for (int i = 0; i < 4; ++i)
        af[i] = *reinterpret_cast<const bf16x8*>(&Al[cur][(wm * 64 + i * 16 + lr) * 64 + cs]);
#pragma unroll
      for (int j = 0; j < 2; ++j)
        bfr[j] = *reinterpret_cast<const bf16x8*>(&Bl[cur][(wn * 32 + j * 16 + lr) * 64 + cs]);
#pragma unroll
      for (int i = 0; i < 4; ++i)
#pragma unroll
        for (int j = 0; j < 2; ++j)
          acc[i][j] = __builtin_amdgcn_mfma_f32_16x16x32_bf16(af[i], bfr[j], acc[i][j], 0, 0, 0);
    }
    asm volatile("" ::: "memory");
    __builtin_amdgcn_s_barrier();
  }

#pragma unroll
  for (int i = 0; i < 4; ++i) {
    int row = m0 + wm * 64 + i * 16 + g * 4;
#pragma unroll
    for (int j = 0; j < 2; ++j) {
      int col = n0 + wn * 32 + j * 16 + lr;
      float bv = bias[col];
#pragma unroll
      for (int r = 0; r < 4; ++r) {
        float v = acc[i][j][r] + bv;
        if (OUT_BF16) ((short*)C)[(size_t)(row + r) * N + col] = f2bf(v);
        else          ((float*)C)[(size_t)(row + r) * N + col] = v;
      }
    }
  }
}

// ---------------- fused masked attention, swapped-operand flash ----------------
// block = (b, h, 128 q-rows); 8 waves x 16 q (q = lane&15 per wave); 16 tiles x 64 keys
__launch_bounds__(512)
__global__ void k_attention(const short* __restrict__ Qp, const short* __restrict__ Kp,
                            const short* __restrict__ Vtg,
                            const unsigned long long* __restrict__ mb,
                            short* __restrict__ O) {
  __shared__ short Kl[2][64 * 64];   // [key][d], chunk-swizzled linear
  __shared__ short Vl[2][64 * 64];   // [d][key], chunk-swizzled linear
  __shared__ short Pl[8][16 * 72];   // per-wave P[q][key] (also output staging)
  const int tid  = threadIdx.x;
  const int lane = tid & 63, wid = tid >> 6;
  const int g = lane >> 4, lr = lane & 15;
  const int bid = blockIdx.x;
  const int qt = bid & 7, h = (bid >> 3) & 15, b = bid >> 7;
  const int qb = qt * 128 + wid * 16;
  const int srow = lane >> 3;
  const int sch  = ((lane & 7) ^ srow) * 8;

  const size_t qrow = (size_t)(b * 1024 + qb + lr);
  // Q fragments (B-operand of S^T = K Q^T): lane holds Q[q=qb+lr][d = db*32 + g*8 + j]
  bf16x8 aq[2];
#pragma unroll
  for (int db = 0; db < 2; ++db)
    aq[db] = *reinterpret_cast<const bf16x8*>(&Qp[qrow * 1024 + h * 64 + db * 32 + g * 8]);

  const unsigned long long* mrow = &mb[qrow * 16];
  const short* Ksrc = &Kp[(size_t)(b * 1024 + wid * 8 + srow) * 1024 + h * 64 + sch];
  const short* Vsrc = &Vtg[(size_t)((b * 16 + h) * 64 + wid * 8 + srow) * 1024 + sch];
  short* Kd0 = &Kl[0][(wid * 8) * 64];
  short* Kd1 = &Kl[1][(wid * 8) * 64];
  short* Vd0 = &Vl[0][(wid * 8) * 64];
  short* Vd1 = &Vl[1][(wid * 8) * 64];

  f32x4 o[4];
#pragma unroll
  for (int d = 0; d < 4; ++d) o[d] = (f32x4){0.f, 0.f, 0.f, 0.f};
  float m_run = -INFINITY, l_run = 0.f, keep = 1.f;

  // prologue stage tile 0
  gll16(Ksrc, Kd0);
  gll16(Vsrc, Vd0);

  for (int kt = 0; kt < 16; ++kt) {
    const int cur = kt & 1;
    if (kt + 1 < 16) {
      gll16(Ksrc + (size_t)(kt + 1) * 64 * 1024, cur ? Kd0 : Kd1);
      gll16(Vsrc + (kt + 1) * 64,                cur ? Vd0 : Vd1);
      asm volatile("s_waitcnt vmcnt(2)" ::: "memory");
    } else {
      asm volatile("s_waitcnt vmcnt(0)" ::: "memory");
    }
    __builtin_amdgcn_s_barrier();
    asm volatile("" ::: "memory");

    const unsigned long long mw = mrow[kt] >> (4 * g);
    if (kt == 0) keep = (mrow[0] & 1ull) ? 0.f : 1.f;

    // S^T = K * Q^T : frag kc -> keys kc*16 + 4g + r, q = lr
    f32x4 s[4];
#pragma unroll
    for (int kc = 0; kc < 4; ++kc) {
      f32x4 a = (f32x4){0.f, 0.f, 0.f, 0.f};
#pragma unroll
      for (int db = 0; db < 2; ++db) {
        bf16x8 kf = *reinterpret_cast<const bf16x8*>(
            &Kl[cur][(kc * 16 + lr) * 64 + (((db * 4 + g) ^ (lr & 7)) * 8)]);
        a = __builtin_amdgcn_mfma_f32_16x16x32_bf16(kf, aq[db], a, 0, 0, 0);
      }
      s[kc] = a;
    }

    // scale + mask + per-q (lane-local) online softmax
    float tmax = -INFINITY;
#pragma unroll
    for (int kc = 0; kc < 4; ++kc)
#pragma unroll
      for (int r = 0; r < 4; ++r) {
        float v = s[kc][r] * 0.125f;
        if ((mw >> (kc * 16 + r)) & 1ull) v = -1e9f;
        s[kc][r] = v;
        tmax = fmaxf(tmax, v);
      }
    tmax = fmaxf(tmax, __shfl_xor(tmax, 16));
    tmax = fmaxf(tmax, __shfl_xor(tmax, 32));
    const float m2 = fmaxf(m_run, tmax);
    const float sc = __expf(m_run - m2);       // first tile: exp(-inf)=0
    float p[4][4], psum = 0.f;
#pragma unroll
    for (int kc = 0; kc < 4; ++kc)
#pragma unroll
      for (int r = 0; r < 4; ++r) {
        float pv = __expf(s[kc][r] - m2);
        p[kc][r] = pv;
        psum += pv;
      }
    psum += __shfl_xor(psum, 16);
    psum += __shfl_xor(psum, 32);
    l_run = l_run * sc + psum;
    m_run = m2;
#pragma unroll
    for (int d = 0; d < 4; ++d)
#pragma unroll
      for (int r = 0; r < 4; ++r) o[d][r] *= sc;

    // P -> LDS as bf16 pairs: Pl[wid][q=lr][key = kc*16 + 4g + 2h (+1)]
    {
      short* Pw = &Pl[wid][lr * 72 + 4 * g];
#pragma unroll
      for (int kc = 0; kc < 4; ++kc)
#pragma unroll
        for (int hh = 0; hh < 2; ++hh)
          *reinterpret_cast<unsigned*>(&Pw[kc * 16 + 2 * hh]) =
              pack_bf2(p[kc][2 * hh], p[kc][2 * hh + 1]);
    }

    // O^T += V^T * P^T
#pragma unroll
    for (int kb = 0; kb < 2; ++kb) {
      bf16x8 pa = *reinterpret_cast<const bf16x8*>(&Pl[wid][lr * 72 + kb * 32 + g * 8]);
      const int cs = ((kb * 4 + g) ^ (lr & 7)) * 8;
#pragma unroll
      for (int d = 0; d < 4; ++d) {
        bf16x8 vf = *reinterpret_cast<const bf16x8*>(&Vl[cur][(d * 16 + lr) * 64 + cs]);
        o[d] = __builtin_amdgcn_mfma_f32_16x16x32_bf16(vf, pa, o[d], 0, 0, 0);
      }
    }
    asm volatile("" ::: "memory");
    __builtin_amdgcn_s_barrier();
  }

  // epilogue: normalize + redundant row-keep, transpose via per-wave LDS, store
  const float inv = keep / l_run;
  {
    short* Ow = &Pl[wid][lr * 72 + 4 * g];
#pragma unroll
    for (int d = 0; d < 4; ++d)
#pragma unroll
      for (int hh = 0; hh < 2; ++hh)
        *reinterpret_cast<unsigned*>(&Ow[d * 16 + 2 * hh]) =
            pack_bf2(o[d][2 * hh] * inv, o[d][2 * hh + 1] * inv);
  }
#pragma unroll
  for (int it = 0; it < 2; ++it) {
    int qq = it * 8 + srow;
    bf16x8 val = *reinterpret_cast<const bf16x8*>(&Pl[wid][qq * 72 + (lane & 7) * 8]);
    *reinterpret_cast<bf16x8*>(
        &O[(size_t)(b * 1024 + qt * 128 + wid * 16 + qq) * 1024 + h * 64 + (lane & 7) * 8]) = val;
  }
}

extern "C" void kernel_launch(void* const* d_in, const int* in_sizes, int n_in,
                              void* d_out, int out_size, void* d_ws, size_t ws_size,
                              hipStream_t stream) {
  const float* query  = (const float*)d_in[0];
  const float* key_in = (const float*)d_in[1];
  const void*  mask_raw = d_in[2];
  const float* Wq = (const float*)d_in[3];
  const float* bq = (const float*)d_in[4];
  const float* Wk = (const float*)d_in[5];
  const float* bk = (const float*)d_in[6];
  const float* Wp = (const float*)d_in[7];
  const float* bp = (const float*)d_in[8];

  char* ws = (char*)d_ws;
  size_t off = 0;
  auto alloc = [&](size_t bytes) {
    char* p = ws + off;
    off = (off + bytes + 255) & ~(size_t)255;
    return p;
  };
  int*   flag  = (int*)alloc(256);
  unsigned long long* packb = (unsigned long long*)alloc(512ull << 10); // [4][1024][16] u64
  short* Qbf   = (short*)alloc(8ull << 20);
  short* Kbf   = (short*)alloc(8ull << 20);   // reused as AttnO
  short* Wt    = (short*)alloc(2ull << 20);
  short* Qproj = (short*)alloc(8ull << 20);
  short* Kproj = (short*)alloc(8ull << 20);
  short* Vtg   = (short*)alloc(8ull << 20);
  short* AttnO = Kbf;

  k_detect_mask<<<1, 64, 0, stream>>>((const unsigned*)mask_raw, flag);
  k_pack_mask<<<16384, 256, 0, stream>>>(mask_raw, flag, packb);
  k_cvt_bf16<<<1024, 256, 0, stream>>>(query, Qbf, (4 * 1024 * 1024) / 4);
  k_cvt_bf16<<<1024, 256, 0, stream>>>(key_in, Kbf, (4 * 1024 * 1024) / 4);

  dim3 tb(32, 8), tg(32, 32);
  dim3 gb(16, 32);  // N/64, M/128

  k_transpose_cvt<<<tg, tb, 0, stream>>>(Wq, Wt);
  k_gemm<1><<<gb, 256, 0, stream>>>(Qbf, Wt, bq, Qproj, 4096, 1024, 1024);
  k_transpose_cvt<<<tg, tb, 0, stream>>>(Wk, Wt);
  k_gemm<1><<<gb, 256, 0, stream>>>(Kbf, Wt, bk, Kproj, 4096, 1024, 1024);

  k_vt_transpose<<<dim3(16, 16, 4), 256, 0, stream>>>(Qproj, Vtg);
  k_attention<<<512, 512, 0, stream>>>(Qproj, Kproj, Vtg, packb, AttnO);

  k_transpose_cvt<<<tg, tb, 0, stream>>>(Wp, Wt);
  k_gemm<0><<<gb, 256, 0, stream>>>(AttnO, Wt, bp, (float*)d_out, 4096, 1024, 1024);
}